// Round 21
// baseline (62.966 us; speedup 1.0000x reference)
//
#include <hip/hip_runtime.h>
#include <math.h>

#define NNODE 32768
#define STHR  1024
#define BTHR  1024   // k_fused block: 16 waves, 1 block/CU (90 KB LDS)
#define FGRID 256    // co-resident persistent grid (1 block/CU x 256 CU)
#define LDSF  1600   // LDS triangle capacity (F = 1538)
#define NL1   64     // level-1 completion counters (64B apart)
#define CREW  8      // sum-crew blocks (last 8 level-2 arrivals)

// fast guarded reciprocal (distance path only; branch boundaries are continuous)
__device__ __forceinline__ float rguard(float d) {
    float dd = (fabsf(d) < 1e-12f) ? 1e-12f : d;
    return __builtin_amdgcn_rcpf(dd);
}

__device__ __forceinline__ void cell_of(float px, float py, float pz,
                                        int& x0, int& y0, int& z0,
                                        float& wx, float& wy, float& wz) {
#pragma clang fp contract(off)
    float fx = (px + 1.0f) * 0.5f * 31.0f;
    float fy = (py + 1.0f) * 0.5f * 31.0f;
    float fz = (pz + 1.0f) * 0.5f * 31.0f;
    float x0f = floorf(fx), y0f = floorf(fy), z0f = floorf(fz);
    wx = fx - x0f; wy = fy - y0f; wz = fz - z0f;
    x0 = (int)fmaxf(fminf(x0f, 33.0f), -2.0f);
    y0 = (int)fmaxf(fminf(y0f, 33.0f), -2.0f);
    z0 = (int)fmaxf(fminf(z0f, 33.0f), -2.0f);
}

// block-cooperative bbox of hull 1 (any blockDim multiple of 64, <=1024)
__device__ __forceinline__ void bbox_of(const float* __restrict__ verts, int V,
                                        float& ocx, float& ocy, float& ocz,
                                        float& osc) {
#pragma clang fp contract(off)
    const float* v1 = verts + (size_t)V * 3;  // hull 1
    float mn[3] = {1e30f, 1e30f, 1e30f};
    float mx[3] = {-1e30f, -1e30f, -1e30f};
    for (int i = threadIdx.x; i < V; i += blockDim.x) {
        for (int c = 0; c < 3; ++c) {
            float val = v1[i * 3 + c];
            mn[c] = fminf(mn[c], val);
            mx[c] = fmaxf(mx[c], val);
        }
    }
    for (int off = 32; off >= 1; off >>= 1) {
        for (int c = 0; c < 3; ++c) {
            mn[c] = fminf(mn[c], __shfl_down(mn[c], off));
            mx[c] = fmaxf(mx[c], __shfl_down(mx[c], off));
        }
    }
    __shared__ float smn[16][3], smx[16][3];
    int wv = threadIdx.x >> 6, lane = threadIdx.x & 63;
    if (lane == 0)
        for (int c = 0; c < 3; ++c) { smn[wv][c] = mn[c]; smx[wv][c] = mx[c]; }
    __syncthreads();
    const int nw = (int)blockDim.x >> 6;
    float ext = -1e30f, cc[3];
    for (int c = 0; c < 3; ++c) {
        float lo = 1e30f, hi = -1e30f;
        for (int w = 0; w < nw; ++w) {
            lo = fminf(lo, smn[w][c]);
            hi = fmaxf(hi, smx[w][c]);
        }
        cc[c] = (lo + hi) * 0.5f;
        ext = fmaxf(ext, hi - lo);
    }
    ocx = cc[0]; ocy = cc[1]; ocz = cc[2];
    osc = (1.0f + 0.2f) * 0.5f * ext;
    __syncthreads();
}

// per-(node, triangle) update — byte-identical to the r19 (43.99us, absmax 0.0)
// version. Distance path: precomputed-dot rewrites (continuous only); parity
// path bit-exact (ab, ac, ap, inv, det as reference).
__device__ __forceinline__ void tri_node(
        float ax, float ay, float az, float abx, float aby, float abz,
        float acx, float acy, float acz, float inv, float det,
        float dbb, float dbc, float dcc,
        float px, float py, float pz, float& mind2, int& h) {
    float apx = px - ax, apy = py - ay, apz = pz - az;
    {
#pragma clang fp contract(fast)
        float d1 = abx * apx + aby * apy + abz * apz;
        float d2 = acx * apx + acy * apy + acz * apz;
        float d3 = d1 - dbb;   // ab.(p-b)
        float d4 = d2 - dbc;   // ac.(p-b)
        float d5 = d1 - dbc;   // ab.(p-c)
        float d6 = d2 - dcc;   // ac.(p-c)
        float vc = d1 * d4 - d3 * d2;
        float vb = d5 * d2 - d1 * d6;
        float va = d3 * d6 - d5 * d4;
        float denom = va + vb + vc;
        float rd = rguard(denom);
        float v_in = vb * rd, w_in = vc * rd;
        float rx = ax + abx * v_in + acx * w_in;
        float ry = ay + aby * v_in + acy * w_in;
        float rz = az + abz * v_in + acz * w_in;
        if (va <= 0.0f && (d4 - d3) >= 0.0f && (d5 - d6) >= 0.0f) {
            float w2 = (d4 - d3) * rguard((d4 - d3) + (d5 - d6));
            rx = ax + abx + (acx - abx) * w2;   // b + (c-b)*w
            ry = ay + aby + (acy - aby) * w2;
            rz = az + abz + (acz - abz) * w2;
        }
        if (vb <= 0.0f && d2 >= 0.0f && d6 <= 0.0f) {
            float w2 = d2 * rguard(d2 - d6);
            rx = ax + acx * w2; ry = ay + acy * w2; rz = az + acz * w2;
        }
        if (vc <= 0.0f && d1 >= 0.0f && d3 <= 0.0f) {
            float w2 = d1 * rguard(d1 - d3);
            rx = ax + abx * w2; ry = ay + aby * w2; rz = az + abz * w2;
        }
        if (d6 >= 0.0f && d5 <= d6) { rx = ax + acx; ry = ay + acy; rz = az + acz; }
        if (d3 >= 0.0f && d4 <= d3) { rx = ax + abx; ry = ay + aby; rz = az + abz; }
        if (d1 <= 0.0f && d2 <= 0.0f) { rx = ax; ry = ay; rz = az; }
        float ddx = px - rx, ddy = py - ry, ddz = pz - rz;
        mind2 = fminf(mind2, ddx * ddx + ddy * ddy + ddz * ddz);
    }
    {
#pragma clang fp contract(off)
        float u = (apy * (-acz) + apz * acy) * inv;
        float qx = apy * abz - apz * aby;
        float qy = apz * abx - apx * abz;
        float qz = apx * aby - apy * abx;
        float v = qx * inv;
        float tt = (acx * qx + acy * qy + acz * qz) * inv;
        h += (fabsf(det) > 1e-9f && u >= 0.0f && u <= 1.0f && v >= 0.0f &&
              (u + v) <= 1.0f && tt > 0.0f) ? 1 : 0;
    }
}

// ---- setup (3 x 1024): block0 = bitmap mark+compact + init listed d2b/hits
//      + counters; blocks 1..2 = triangle records (r19-identical). ----
__global__ void __launch_bounds__(STHR) k_setup(
        const float* __restrict__ verts, const int* __restrict__ faces,
        float* __restrict__ tri, unsigned int* __restrict__ d2b,
        int* __restrict__ hits, int* __restrict__ cnt,
        unsigned long long* __restrict__ acc, int* __restrict__ done2,
        int* __restrict__ lvl1, int* __restrict__ lvl2,
        int* __restrict__ list, int V, int F) {
    float cx0, cy0, cz0, sc;
    bbox_of(verts, V, cx0, cy0, cz0, sc);
    const int b = (int)blockIdx.x, tid = threadIdx.x;

    if (b == 0) {
        __shared__ unsigned bm[NNODE / 32];   // 1024 words, one per thread
        __shared__ int scnt[STHR];
        bm[tid] = 0u;
        __syncthreads();
        for (int i = tid; i < V; i += STHR) {
#pragma clang fp contract(off)
            float px = (verts[i * 3 + 0] - cx0) / sc;  // hull-0 vertex
            float py = (verts[i * 3 + 1] - cy0) / sc;
            float pz = (verts[i * 3 + 2] - cz0) / sc;
            int x0, y0, z0; float wx, wy, wz;
            cell_of(px, py, pz, x0, y0, z0, wx, wy, wz);
            for (int k = 0; k < 8; ++k) {
                int zi = z0 + ((k >> 2) & 1), yi = y0 + ((k >> 1) & 1),
                    xi = x0 + (k & 1);
                if ((unsigned)zi < 32u && (unsigned)yi < 32u && (unsigned)xi < 32u) {
                    int node = (zi * 32 + yi) * 32 + xi;
                    atomicOr(&bm[node >> 5], 1u << (node & 31));
                }
            }
        }
        __syncthreads();
        unsigned w0 = bm[tid];
        int c = __popc(w0);
        scnt[tid] = c;
        __syncthreads();
        for (int off = 1; off < STHR; off <<= 1) {  // Hillis-Steele inclusive scan
            int v_ = (tid >= off) ? scnt[tid - off] : 0;
            __syncthreads();
            scnt[tid] += v_;
            __syncthreads();
        }
        int total = scnt[STHR - 1];
        if (tid == STHR - 1) cnt[0] = total;
        int off = scnt[tid] - c;
        int basebit = tid * 32;
        while (w0) {
            int bb = __ffs(w0) - 1;
            list[off++] = basebit + bb;
            w0 &= w0 - 1;
        }
        __syncthreads();
        for (int t = tid; t < total; t += STHR) {   // init ONLY listed nodes
            int nd = list[t];
            d2b[nd] = 0xFFFFFFFFu;
            hits[nd] = 0;
        }
        if (tid < NL1) lvl1[tid * 16] = 0;          // 64B-spread counters
        if (tid == 0) { acc[0] = 0ull; done2[0] = 0; lvl2[0] = 0; }
    } else {
        // record: a(3) ab(3) ac(3) inv det |ab|^2 ab.ac |ac|^2 pad pad
        int f = (b - 1) * STHR + tid;
        if (f < F) {
#pragma clang fp contract(off)
            const float* v1 = verts + (size_t)V * 3;
            int i0 = faces[f * 3 + 0], i1 = faces[f * 3 + 1], i2 = faces[f * 3 + 2];
            float ax = (v1[i0 * 3 + 0] - cx0) / sc, ay = (v1[i0 * 3 + 1] - cy0) / sc,
                  az = (v1[i0 * 3 + 2] - cz0) / sc;
            float bx = (v1[i1 * 3 + 0] - cx0) / sc, by = (v1[i1 * 3 + 1] - cy0) / sc,
                  bz = (v1[i1 * 3 + 2] - cz0) / sc;
            float cx = (v1[i2 * 3 + 0] - cx0) / sc, cy = (v1[i2 * 3 + 1] - cy0) / sc,
                  cz = (v1[i2 * 3 + 2] - cz0) / sc;
            float abx = bx - ax, aby = by - ay, abz = bz - az;
            float acx = cx - ax, acy = cy - ay, acz = cz - az;
            float det = aby * (-acz) + abz * acy;
            float dd = (fabsf(det) < 1e-12f) ? 1e-12f : det;
            float inv = 1.0f / dd;  // IEEE — parity test must stay bit-exact
            float* r = tri + (size_t)f * 16;
            r[0] = ax;  r[1] = ay;  r[2] = az;
            r[3] = abx; r[4] = aby; r[5] = abz;
            r[6] = acx; r[7] = acy; r[8] = acz;
            r[9] = inv; r[10] = det;
            r[11] = abx * abx + aby * aby + abz * abz;
            r[12] = abx * acx + aby * acy + abz * acz;
            r[13] = acx * acx + acy * acy + acz * acz;
            r[14] = 0.0f; r[15] = 0.0f;
        }
    }
}

// ---- fused main+sum: 256 blocks x 16 waves; the WHOLE triangle set staged
//      ONCE into 90 KB LDS (1 block/CU); then waves free-run over
//      (node, F-half) items with ZERO barriers (r20 lesson: the 2-barriers-
//      per-item skeleton left 60% of time in vmcnt drains at barriers).
//      One atomic pair per item (r11: spread atomics are cheap). ----
__global__ void __launch_bounds__(BTHR) k_fused(
        const float* __restrict__ tri, const int* __restrict__ list,
        const int* __restrict__ cnt, unsigned int* __restrict__ d2b,
        int* __restrict__ hits, int* __restrict__ lvl1, int* __restrict__ lvl2,
        unsigned long long* __restrict__ acc, int* __restrict__ done2,
        const float* __restrict__ verts, float* __restrict__ out,
        int F, int V) {
    __shared__ float s[14][LDSF];
    const int tid = threadIdx.x, lane = tid & 63, wv = tid >> 6;

    // stage the entire triangle set, SoA (lanes write consecutive j: no conflict)
    for (int j = tid; j < F; j += BTHR) {
        const float4* g = (const float4*)(tri + (size_t)j * 16);
        float4 r0 = g[0], r1 = g[1], r2 = g[2], r3 = g[3];
        s[0][j] = r0.x;  s[1][j] = r0.y;  s[2][j] = r0.z;  s[3][j] = r0.w;
        s[4][j] = r1.x;  s[5][j] = r1.y;  s[6][j] = r1.z;  s[7][j] = r1.w;
        s[8][j] = r2.x;  s[9][j] = r2.y;  s[10][j] = r2.z; s[11][j] = r2.w;
        s[12][j] = r3.x; s[13][j] = r3.y;
    }
    __syncthreads();   // the ONLY barrier before completion

    const int n = cnt[0];
    const int nitems = n * 2;                       // (node, F-half)
    const int wgid = (int)blockIdx.x * 16 + wv;     // 0..4095
    const int nb64 = (F + 63) >> 6;                 // 64-blocks of triangles
    const int nb0 = (nb64 + 1) >> 1;                // first half gets ceil

    for (int it = wgid; it < nitems; it += FGRID * 16) {
        const int nodeIdx = it >> 1;
        const int half = it & 1;
        const int f0 = half ? nb0 * 64 : 0;
        const int f1 = half ? F : nb0 * 64;
        const int node = list[nodeIdx];
        float px, py, pz;
        {
#pragma clang fp contract(off)
            px = (float)((double)(node & 31) * (2.0 / 31.0) - 1.0);
            py = (float)((double)((node >> 5) & 31) * (2.0 / 31.0) - 1.0);
            pz = (float)((double)(node >> 10) * (2.0 / 31.0) - 1.0);
        }
        float m = 1e30f;
        int h = 0;
        for (int j0 = f0; j0 < f1; j0 += 64) {
            int j = j0 + lane;
            if (j < f1) {
                tri_node(s[0][j], s[1][j], s[2][j], s[3][j], s[4][j], s[5][j],
                         s[6][j], s[7][j], s[8][j], s[9][j], s[10][j],
                         s[11][j], s[12][j], s[13][j], px, py, pz, m, h);
            }
        }
        for (int off = 32; off >= 1; off >>= 1) {
            m = fminf(m, __shfl_xor(m, off));
            h += __shfl_xor(h, off);
        }
        if (lane == 0) {
            atomicMin(d2b + node, __float_as_uint(m));
            atomicAdd(hits + node, h);
        }
    }

    // ---- completion: drain, then hierarchical relaxed counters (no fences) ----
    __shared__ int crew_slice;
    __syncthreads();       // s_waitcnt vmcnt(0) before s_barrier: atomics done
    if (tid == 0) {
        crew_slice = -1;
        int cohort = (int)blockIdx.x & (NL1 - 1);
        int quota = (FGRID + NL1 - 1 - cohort) / NL1;       // = 4 for FGRID=256
        int p1 = atomicAdd(&lvl1[cohort * 16], 1);
        if (p1 == quota - 1) {                              // cohort finisher
            int p2 = atomicAdd(lvl2, 1);
            if (p2 >= NL1 - CREW) {                         // last 8 arrivals
                while (__hip_atomic_load(lvl2, __ATOMIC_RELAXED,
                                         __HIP_MEMORY_SCOPE_AGENT) < NL1)
                    __builtin_amdgcn_s_sleep(1);
                crew_slice = p2 - (NL1 - CREW);             // 0..7
            }
        }
    }
    __syncthreads();
    const int slice = crew_slice;
    if (slice < 0) return;

    // ---- sum slice (8 crew blocks x 1024 thr): trilinear gather ----
    float cx, cy, cz, sc;
    bbox_of(verts, V, cx, cy, cz, sc);
    float val = 0.0f;
    {
#pragma clang fp contract(off)
        for (int i = slice * BTHR + tid; i < V; i += CREW * BTHR) {
            float px = (verts[i * 3 + 0] - cx) / sc;
            float py = (verts[i * 3 + 1] - cy) / sc;
            float pz = (verts[i * 3 + 2] - cz) / sc;
            int x0, y0, z0; float wx, wy, wz;
            cell_of(px, py, pz, x0, y0, z0, wx, wy, wz);
            auto corner = [&](int zi, int yi, int xi, float w) -> float {
#pragma clang fp contract(off)
                bool valid = (zi >= 0) && (zi <= 31) && (yi >= 0) && (yi <= 31) &&
                             (xi >= 0) && (xi <= 31);
                int zc = min(max(zi, 0), 31);
                int yc = min(max(yi, 0), 31);
                int xc = min(max(xi, 0), 31);
                int idx = (zc * 32 + yc) * 32 + xc;
                unsigned dbits = __hip_atomic_load(&d2b[idx], __ATOMIC_RELAXED,
                                                   __HIP_MEMORY_SCOPE_AGENT);
                int hh = __hip_atomic_load(&hits[idx], __ATOMIC_RELAXED,
                                           __HIP_MEMORY_SCOPE_AGENT);
                float vv = (hh & 1) ? sqrtf(fmaxf(__uint_as_float(dbits), 0.0f))
                                    : 0.0f;
                return valid ? vv * w : 0.0f;
            };
            val += corner(z0, y0, x0, (1.0f - wz) * (1.0f - wy) * (1.0f - wx))
                 + corner(z0, y0, x0 + 1, (1.0f - wz) * (1.0f - wy) * wx)
                 + corner(z0, y0 + 1, x0, (1.0f - wz) * wy * (1.0f - wx))
                 + corner(z0, y0 + 1, x0 + 1, (1.0f - wz) * wy * wx)
                 + corner(z0 + 1, y0, x0, wz * (1.0f - wy) * (1.0f - wx))
                 + corner(z0 + 1, y0, x0 + 1, wz * (1.0f - wy) * wx)
                 + corner(z0 + 1, y0 + 1, x0, wz * wy * (1.0f - wx))
                 + corner(z0 + 1, y0 + 1, x0 + 1, wz * wy * wx);
        }
    }
    __shared__ float sm[BTHR];
    sm[tid] = val;
    __syncthreads();
    for (int ss = BTHR / 2; ss >= 1; ss >>= 1) {
        if (tid < ss) sm[tid] += sm[tid + ss];
        __syncthreads();
    }
    if (tid == 0) {
        unsigned long long fx =
            (unsigned long long)((double)sm[0] * 4294967296.0);  // 2^32 fixed-point
        atomicAdd(acc, fx);
        asm volatile("s_waitcnt vmcnt(0)");   // value-add at LLC before counter
        int prev = atomicAdd(done2, 1);
        if (prev == CREW - 1) {
            unsigned long long tot = atomicAdd(acc, 0ull);   // RMW read at LLC
            out[0] = (float)((double)tot / 4294967296.0 * 0.25);  // / H^2, H=2
        }
    }
}

extern "C" void kernel_launch(void* const* d_in, const int* in_sizes, int n_in,
                              void* d_out, int out_size, void* d_ws, size_t ws_size,
                              hipStream_t stream) {
    const float* verts = (const float*)d_in[0];
    const int* faces = (const int*)d_in[1];
    float* out = (float*)d_out;
    float* ws = (float*)d_ws;

    int V = in_sizes[0] / 6;  // 2 hulls x 3 comps
    int F = in_sizes[1] / 3;
    if (F > LDSF) F = LDSF;   // LDS capacity guard (F = 1538 for this problem)

    unsigned long long* acc = (unsigned long long*)ws;   // ws[0..1]
    int* done2 = (int*)(ws + 2);
    int* cnt = (int*)(ws + 3);
    int* lvl2 = (int*)(ws + 4);
    int* lvl1 = (int*)(ws + 16);                         // 64 counters, stride 16
    float* tri = ws + 16 + NL1 * 16;                     // 16B-aligned
    unsigned int* d2b = (unsigned int*)(tri + 16 * (size_t)F);
    int* hits = (int*)(d2b + NNODE);
    int* list = hits + NNODE;                            // NNODE ints max

    int nrec = (F + STHR - 1) / STHR;

    k_setup<<<1 + nrec, STHR, 0, stream>>>(verts, faces, tri, d2b, hits, cnt, acc,
                                           done2, lvl1, lvl2, list, V, F);
    k_fused<<<FGRID, BTHR, 0, stream>>>(tri, list, cnt, d2b, hits, lvl1, lvl2, acc,
                                        done2, verts, out, F, V);
}

// Round 22
// 43.691 us; speedup vs baseline: 1.4412x; 1.4412x over previous
//
#include <hip/hip_runtime.h>
#include <math.h>

#define NNODE 32768
#define NTHR  256
#define STHR  1024
#define CH    256    // floor-partition chunk; remainder (<64) absorbed into last
#define MAXC  (CH + 63)
#define FGRID 2048   // persistent k_fused grid
#define NL1   64     // level-1 completion counters (64B apart)
#define CREW  8      // sum-crew blocks (last 8 level-2 arrivals)

// fast guarded reciprocal (distance path only; branch boundaries are continuous)
__device__ __forceinline__ float rguard(float d) {
    float dd = (fabsf(d) < 1e-12f) ? 1e-12f : d;
    return __builtin_amdgcn_rcpf(dd);
}

__device__ __forceinline__ void cell_of(float px, float py, float pz,
                                        int& x0, int& y0, int& z0,
                                        float& wx, float& wy, float& wz) {
#pragma clang fp contract(off)
    float fx = (px + 1.0f) * 0.5f * 31.0f;
    float fy = (py + 1.0f) * 0.5f * 31.0f;
    float fz = (pz + 1.0f) * 0.5f * 31.0f;
    float x0f = floorf(fx), y0f = floorf(fy), z0f = floorf(fz);
    wx = fx - x0f; wy = fy - y0f; wz = fz - z0f;
    x0 = (int)fmaxf(fminf(x0f, 33.0f), -2.0f);
    y0 = (int)fmaxf(fminf(y0f, 33.0f), -2.0f);
    z0 = (int)fmaxf(fminf(z0f, 33.0f), -2.0f);
}

// block-cooperative bbox of hull 1 (any blockDim multiple of 64, <=1024)
__device__ __forceinline__ void bbox_of(const float* __restrict__ verts, int V,
                                        float& ocx, float& ocy, float& ocz,
                                        float& osc) {
#pragma clang fp contract(off)
    const float* v1 = verts + (size_t)V * 3;  // hull 1
    float mn[3] = {1e30f, 1e30f, 1e30f};
    float mx[3] = {-1e30f, -1e30f, -1e30f};
    for (int i = threadIdx.x; i < V; i += blockDim.x) {
        for (int c = 0; c < 3; ++c) {
            float val = v1[i * 3 + c];
            mn[c] = fminf(mn[c], val);
            mx[c] = fmaxf(mx[c], val);
        }
    }
    for (int off = 32; off >= 1; off >>= 1) {
        for (int c = 0; c < 3; ++c) {
            mn[c] = fminf(mn[c], __shfl_down(mn[c], off));
            mx[c] = fmaxf(mx[c], __shfl_down(mx[c], off));
        }
    }
    __shared__ float smn[16][3], smx[16][3];
    int wv = threadIdx.x >> 6, lane = threadIdx.x & 63;
    if (lane == 0)
        for (int c = 0; c < 3; ++c) { smn[wv][c] = mn[c]; smx[wv][c] = mx[c]; }
    __syncthreads();
    const int nw = (int)blockDim.x >> 6;
    float ext = -1e30f, cc[3];
    for (int c = 0; c < 3; ++c) {
        float lo = 1e30f, hi = -1e30f;
        for (int w = 0; w < nw; ++w) {
            lo = fminf(lo, smn[w][c]);
            hi = fmaxf(hi, smx[w][c]);
        }
        cc[c] = (lo + hi) * 0.5f;
        ext = fmaxf(ext, hi - lo);
    }
    ocx = cc[0]; ocy = cc[1]; ocz = cc[2];
    osc = (1.0f + 0.2f) * 0.5f * ext;
    __syncthreads();
}

// per-(node, triangle) update — byte-identical math to r19 (43.99us, absmax 0.0).
__device__ __forceinline__ void tri_node(
        float ax, float ay, float az, float abx, float aby, float abz,
        float acx, float acy, float acz, float inv, float det,
        float dbb, float dbc, float dcc,
        float px, float py, float pz, float& mind2, int& h) {
    float apx = px - ax, apy = py - ay, apz = pz - az;
    {
#pragma clang fp contract(fast)
        float d1 = abx * apx + aby * apy + abz * apz;
        float d2 = acx * apx + acy * apy + acz * apz;
        float d3 = d1 - dbb;   // ab.(p-b)
        float d4 = d2 - dbc;   // ac.(p-b)
        float d5 = d1 - dbc;   // ab.(p-c)
        float d6 = d2 - dcc;   // ac.(p-c)
        float vc = d1 * d4 - d3 * d2;
        float vb = d5 * d2 - d1 * d6;
        float va = d3 * d6 - d5 * d4;
        float denom = va + vb + vc;
        float rd = rguard(denom);
        float v_in = vb * rd, w_in = vc * rd;
        float rx = ax + abx * v_in + acx * w_in;
        float ry = ay + aby * v_in + acy * w_in;
        float rz = az + abz * v_in + acz * w_in;
        if (va <= 0.0f && (d4 - d3) >= 0.0f && (d5 - d6) >= 0.0f) {
            float w2 = (d4 - d3) * rguard((d4 - d3) + (d5 - d6));
            rx = ax + abx + (acx - abx) * w2;   // b + (c-b)*w
            ry = ay + aby + (acy - aby) * w2;
            rz = az + abz + (acz - abz) * w2;
        }
        if (vb <= 0.0f && d2 >= 0.0f && d6 <= 0.0f) {
            float w2 = d2 * rguard(d2 - d6);
            rx = ax + acx * w2; ry = ay + acy * w2; rz = az + acz * w2;
        }
        if (vc <= 0.0f && d1 >= 0.0f && d3 <= 0.0f) {
            float w2 = d1 * rguard(d1 - d3);
            rx = ax + abx * w2; ry = ay + aby * w2; rz = az + abz * w2;
        }
        if (d6 >= 0.0f && d5 <= d6) { rx = ax + acx; ry = ay + acy; rz = az + acz; }
        if (d3 >= 0.0f && d4 <= d3) { rx = ax + abx; ry = ay + aby; rz = az + abz; }
        if (d1 <= 0.0f && d2 <= 0.0f) { rx = ax; ry = ay; rz = az; }
        float ddx = px - rx, ddy = py - ry, ddz = pz - rz;
        mind2 = fminf(mind2, ddx * ddx + ddy * ddy + ddz * ddz);
    }
    {
#pragma clang fp contract(off)
        float u = (apy * (-acz) + apz * acy) * inv;
        float qx = apy * abz - apz * aby;
        float qy = apz * abx - apx * abz;
        float qz = apx * aby - apy * abx;
        float v = qx * inv;
        float tt = (acx * qx + acy * qy + acz * qz) * inv;
        h += (fabsf(det) > 1e-9f && u >= 0.0f && u <= 1.0f && v >= 0.0f &&
              (u + v) <= 1.0f && tt > 0.0f) ? 1 : 0;
    }
}

// ---- setup (3 x 1024): r19-identical. ----
__global__ void __launch_bounds__(STHR) k_setup(
        const float* __restrict__ verts, const int* __restrict__ faces,
        float* __restrict__ tri, unsigned int* __restrict__ d2b,
        int* __restrict__ hits, int* __restrict__ cnt,
        unsigned long long* __restrict__ acc, int* __restrict__ done2,
        int* __restrict__ lvl1, int* __restrict__ lvl2,
        int* __restrict__ list, int V, int F) {
    float cx0, cy0, cz0, sc;
    bbox_of(verts, V, cx0, cy0, cz0, sc);
    const int b = (int)blockIdx.x, tid = threadIdx.x;

    if (b == 0) {
        __shared__ unsigned bm[NNODE / 32];   // 1024 words, one per thread
        __shared__ int scnt[STHR];
        bm[tid] = 0u;
        __syncthreads();
        for (int i = tid; i < V; i += STHR) {
#pragma clang fp contract(off)
            float px = (verts[i * 3 + 0] - cx0) / sc;  // hull-0 vertex
            float py = (verts[i * 3 + 1] - cy0) / sc;
            float pz = (verts[i * 3 + 2] - cz0) / sc;
            int x0, y0, z0; float wx, wy, wz;
            cell_of(px, py, pz, x0, y0, z0, wx, wy, wz);
            for (int k = 0; k < 8; ++k) {
                int zi = z0 + ((k >> 2) & 1), yi = y0 + ((k >> 1) & 1),
                    xi = x0 + (k & 1);
                if ((unsigned)zi < 32u && (unsigned)yi < 32u && (unsigned)xi < 32u) {
                    int node = (zi * 32 + yi) * 32 + xi;
                    atomicOr(&bm[node >> 5], 1u << (node & 31));
                }
            }
        }
        __syncthreads();
        unsigned w0 = bm[tid];
        int c = __popc(w0);
        scnt[tid] = c;
        __syncthreads();
        for (int off = 1; off < STHR; off <<= 1) {  // Hillis-Steele inclusive scan
            int v_ = (tid >= off) ? scnt[tid - off] : 0;
            __syncthreads();
            scnt[tid] += v_;
            __syncthreads();
        }
        int total = scnt[STHR - 1];
        if (tid == STHR - 1) cnt[0] = total;
        int off = scnt[tid] - c;
        int basebit = tid * 32;
        while (w0) {
            int bb = __ffs(w0) - 1;
            list[off++] = basebit + bb;
            w0 &= w0 - 1;
        }
        __syncthreads();
        for (int t = tid; t < total; t += STHR) {   // init ONLY listed nodes
            int nd = list[t];
            d2b[nd] = 0xFFFFFFFFu;
            hits[nd] = 0;
        }
        if (tid < NL1) lvl1[tid * 16] = 0;          // 64B-spread counters
        if (tid == 0) { acc[0] = 0ull; done2[0] = 0; lvl2[0] = 0; }
    } else {
        // record: a(3) ab(3) ac(3) inv det |ab|^2 ab.ac |ac|^2 pad pad
        int f = (b - 1) * STHR + tid;
        if (f < F) {
#pragma clang fp contract(off)
            const float* v1 = verts + (size_t)V * 3;
            int i0 = faces[f * 3 + 0], i1 = faces[f * 3 + 1], i2 = faces[f * 3 + 2];
            float ax = (v1[i0 * 3 + 0] - cx0) / sc, ay = (v1[i0 * 3 + 1] - cy0) / sc,
                  az = (v1[i0 * 3 + 2] - cz0) / sc;
            float bx = (v1[i1 * 3 + 0] - cx0) / sc, by = (v1[i1 * 3 + 1] - cy0) / sc,
                  bz = (v1[i1 * 3 + 2] - cz0) / sc;
            float cx = (v1[i2 * 3 + 0] - cx0) / sc, cy = (v1[i2 * 3 + 1] - cy0) / sc,
                  cz = (v1[i2 * 3 + 2] - cz0) / sc;
            float abx = bx - ax, aby = by - ay, abz = bz - az;
            float acx = cx - ax, acy = cy - ay, acz = cz - az;
            float det = aby * (-acz) + abz * acy;
            float dd = (fabsf(det) < 1e-12f) ? 1e-12f : det;
            float inv = 1.0f / dd;  // IEEE — parity test must stay bit-exact
            float* r = tri + (size_t)f * 16;
            r[0] = ax;  r[1] = ay;  r[2] = az;
            r[3] = abx; r[4] = aby; r[5] = abz;
            r[6] = acx; r[7] = acy; r[8] = acz;
            r[9] = inv; r[10] = det;
            r[11] = abx * abx + aby * aby + abz * abz;
            r[12] = abx * acx + aby * acy + abz * acz;
            r[13] = acx * acx + acy * acy + acz * acz;
            r[14] = 0.0f; r[15] = 0.0f;
        }
    }
}

// ---- fused main+sum: block = (node-group-of-16, chunk); each WAVE owns 4
//      consecutive nodes, so every triangle's 14 LDS reads are amortized over
//      4 tri_node evaluations (r21 diagnosis: 14 reads per (node,tri) made
//      every LDS-inner-loop variant ~4x over the CU's 128 B/cy LDS bandwidth,
//      pinning VALUBusy at 25-40%). Completion machinery r19-identical. ----
__global__ void __launch_bounds__(NTHR) k_fused(
        const float* __restrict__ tri, const int* __restrict__ list,
        const int* __restrict__ cnt, unsigned int* __restrict__ d2b,
        int* __restrict__ hits, int* __restrict__ lvl1, int* __restrict__ lvl2,
        unsigned long long* __restrict__ acc, int* __restrict__ done2,
        const float* __restrict__ verts, float* __restrict__ out,
        int F, int nch, int V) {
    const int n = cnt[0];
    const int ngroups = (n + 15) >> 4;          // node-groups of 16 (4/wave)
    const int total = ngroups * nch;
    const int tid = threadIdx.x, lane = tid & 63, wv = tid >> 6;
    __shared__ float s[14][MAXC];

    for (int item = (int)blockIdx.x; item < total; item += FGRID) {
        const int group = item / nch;
        const int c = item - group * nch;
        const int cbase = c * CH;
        const int tn = (c == nch - 1) ? (F - cbase) : CH;   // last absorbs rem<64

        for (int j = tid; j < tn; j += NTHR) {
            const float4* g = (const float4*)(tri + (size_t)(cbase + j) * 16);
            float4 r0 = g[0], r1 = g[1], r2 = g[2], r3 = g[3];
            s[0][j] = r0.x;  s[1][j] = r0.y;  s[2][j] = r0.z;  s[3][j] = r0.w;
            s[4][j] = r1.x;  s[5][j] = r1.y;  s[6][j] = r1.z;  s[7][j] = r1.w;
            s[8][j] = r2.x;  s[9][j] = r2.y;  s[10][j] = r2.z; s[11][j] = r2.w;
            s[12][j] = r3.x; s[13][j] = r3.y;
        }
        __syncthreads();

        const int idx0 = group * 16 + wv * 4;   // this wave's 4 nodes
        int nd[4];
        float px[4], py[4], pz[4], m[4];
        int h[4];
#pragma unroll
        for (int k = 0; k < 4; ++k) {
            nd[k] = (idx0 + k < n) ? list[idx0 + k] : -1;
            px[k] = 0.0f; py[k] = 0.0f; pz[k] = 0.0f;
            m[k] = 1e30f; h[k] = 0;
            if (nd[k] >= 0) {
#pragma clang fp contract(off)
                px[k] = (float)((double)(nd[k] & 31) * (2.0 / 31.0) - 1.0);
                py[k] = (float)((double)((nd[k] >> 5) & 31) * (2.0 / 31.0) - 1.0);
                pz[k] = (float)((double)(nd[k] >> 10) * (2.0 / 31.0) - 1.0);
            }
        }
        if (nd[0] >= 0) {   // wave-uniform (list is dense)
            for (int mi = 0; mi * 64 < tn; ++mi) {
                int j = lane + mi * 64;
                if (j < tn) {
                    // load the triangle ONCE, use for 4 nodes
                    float ax = s[0][j], ay = s[1][j], az = s[2][j];
                    float abx = s[3][j], aby = s[4][j], abz = s[5][j];
                    float acx = s[6][j], acy = s[7][j], acz = s[8][j];
                    float inv = s[9][j], det = s[10][j];
                    float dbb = s[11][j], dbc = s[12][j], dcc = s[13][j];
#pragma unroll
                    for (int k = 0; k < 4; ++k) {
                        if (nd[k] >= 0)
                            tri_node(ax, ay, az, abx, aby, abz, acx, acy, acz,
                                     inv, det, dbb, dbc, dcc,
                                     px[k], py[k], pz[k], m[k], h[k]);
                    }
                }
            }
        }
#pragma unroll
        for (int k = 0; k < 4; ++k) {
            for (int off = 32; off >= 1; off >>= 1) {
                m[k] = fminf(m[k], __shfl_xor(m[k], off));
                h[k] += __shfl_xor(h[k], off);
            }
        }
        if (lane == 0) {
#pragma unroll
            for (int k = 0; k < 4; ++k) {
                if (nd[k] >= 0) {
                    atomicMin(d2b + nd[k], __float_as_uint(m[k]));
                    atomicAdd(hits + nd[k], h[k]);
                }
            }
        }
        __syncthreads();   // LDS reuse fence before next item's staging
    }

    // ---- completion: drain, then hierarchical relaxed counters (no fences) ----
    __shared__ int crew_slice;
    __syncthreads();       // s_waitcnt vmcnt(0) before s_barrier: atomics done
    if (tid == 0) {
        crew_slice = -1;
        int cohort = (int)blockIdx.x & (NL1 - 1);
        int quota = (FGRID + NL1 - 1 - cohort) / NL1;       // = 32 for FGRID=2048
        int p1 = atomicAdd(&lvl1[cohort * 16], 1);
        if (p1 == quota - 1) {                              // cohort finisher
            int p2 = atomicAdd(lvl2, 1);
            if (p2 >= NL1 - CREW) {                         // last 8 arrivals
                while (__hip_atomic_load(lvl2, __ATOMIC_RELAXED,
                                         __HIP_MEMORY_SCOPE_AGENT) < NL1)
                    __builtin_amdgcn_s_sleep(1);
                crew_slice = p2 - (NL1 - CREW);             // 0..7
            }
        }
    }
    __syncthreads();
    const int slice = crew_slice;
    if (slice < 0) return;

    // ---- sum slice (8 crew blocks): trilinear gather, AGENT-scope reads ----
    float cx, cy, cz, sc;
    bbox_of(verts, V, cx, cy, cz, sc);
    float val = 0.0f;
    {
#pragma clang fp contract(off)
        for (int i = slice * NTHR + tid; i < V; i += CREW * NTHR) {
            float qx = (verts[i * 3 + 0] - cx) / sc;
            float qy = (verts[i * 3 + 1] - cy) / sc;
            float qz = (verts[i * 3 + 2] - cz) / sc;
            int x0, y0, z0; float wx, wy, wz;
            cell_of(qx, qy, qz, x0, y0, z0, wx, wy, wz);
            auto corner = [&](int zi, int yi, int xi, float w) -> float {
#pragma clang fp contract(off)
                bool valid = (zi >= 0) && (zi <= 31) && (yi >= 0) && (yi <= 31) &&
                             (xi >= 0) && (xi <= 31);
                int zc = min(max(zi, 0), 31);
                int yc = min(max(yi, 0), 31);
                int xc = min(max(xi, 0), 31);
                int idx = (zc * 32 + yc) * 32 + xc;
                unsigned dbits = __hip_atomic_load(&d2b[idx], __ATOMIC_RELAXED,
                                                   __HIP_MEMORY_SCOPE_AGENT);
                int hh = __hip_atomic_load(&hits[idx], __ATOMIC_RELAXED,
                                           __HIP_MEMORY_SCOPE_AGENT);
                float vv = (hh & 1) ? sqrtf(fmaxf(__uint_as_float(dbits), 0.0f))
                                    : 0.0f;
                return valid ? vv * w : 0.0f;
            };
            val += corner(z0, y0, x0, (1.0f - wz) * (1.0f - wy) * (1.0f - wx))
                 + corner(z0, y0, x0 + 1, (1.0f - wz) * (1.0f - wy) * wx)
                 + corner(z0, y0 + 1, x0, (1.0f - wz) * wy * (1.0f - wx))
                 + corner(z0, y0 + 1, x0 + 1, (1.0f - wz) * wy * wx)
                 + corner(z0 + 1, y0, x0, wz * (1.0f - wy) * (1.0f - wx))
                 + corner(z0 + 1, y0, x0 + 1, wz * (1.0f - wy) * wx)
                 + corner(z0 + 1, y0 + 1, x0, wz * wy * (1.0f - wx))
                 + corner(z0 + 1, y0 + 1, x0 + 1, wz * wy * wx);
        }
    }
    __shared__ float sm[NTHR];
    sm[tid] = val;
    __syncthreads();
    for (int ss = NTHR / 2; ss >= 1; ss >>= 1) {
        if (tid < ss) sm[tid] += sm[tid + ss];
        __syncthreads();
    }
    if (tid == 0) {
        unsigned long long fx =
            (unsigned long long)((double)sm[0] * 4294967296.0);  // 2^32 fixed-point
        atomicAdd(acc, fx);
        asm volatile("s_waitcnt vmcnt(0)");   // value-add at LLC before counter
        int prev = atomicAdd(done2, 1);
        if (prev == CREW - 1) {
            unsigned long long tot = atomicAdd(acc, 0ull);   // RMW read at LLC
            out[0] = (float)((double)tot / 4294967296.0 * 0.25);  // / H^2, H=2
        }
    }
}

extern "C" void kernel_launch(void* const* d_in, const int* in_sizes, int n_in,
                              void* d_out, int out_size, void* d_ws, size_t ws_size,
                              hipStream_t stream) {
    const float* verts = (const float*)d_in[0];
    const int* faces = (const int*)d_in[1];
    float* out = (float*)d_out;
    float* ws = (float*)d_ws;

    int V = in_sizes[0] / 6;  // 2 hulls x 3 comps
    int F = in_sizes[1] / 3;

    unsigned long long* acc = (unsigned long long*)ws;   // ws[0..1]
    int* done2 = (int*)(ws + 2);
    int* cnt = (int*)(ws + 3);
    int* lvl2 = (int*)(ws + 4);
    int* lvl1 = (int*)(ws + 16);                         // 64 counters, stride 16
    float* tri = ws + 16 + NL1 * 16;                     // 16B-aligned
    unsigned int* d2b = (unsigned int*)(tri + 16 * (size_t)F);
    int* hits = (int*)(d2b + NNODE);
    int* list = hits + NNODE;                            // NNODE ints max

    // floor partition; remainder < 64 absorbed into the last chunk
    int nch = F / CH;
    int rem = F - nch * CH;
    if (nch == 0 || rem >= 64) nch += (rem > 0 ? 1 : 0);
    if (nch == 0) nch = 1;

    int nrec = (F + STHR - 1) / STHR;

    k_setup<<<1 + nrec, STHR, 0, stream>>>(verts, faces, tri, d2b, hits, cnt, acc,
                                           done2, lvl1, lvl2, list, V, F);
    k_fused<<<FGRID, NTHR, 0, stream>>>(tri, list, cnt, d2b, hits, lvl1, lvl2, acc,
                                        done2, verts, out, F, nch, V);
}